// Round 3
// baseline (26542.120 us; speedup 1.0000x reference)
//
#include <hip/hip_runtime.h>
#include <float.h>

#define V 50000
#define E 100
#define H 512
#define T 200
#define B 256
#define NC 5
#define HB (H * B)

// ---------------- activations (fast, ~2e-7 abs err) ----------------
__device__ __forceinline__ float fsig(float x)  { return 1.f / (1.f + __expf(-x)); }
__device__ __forceinline__ float ftanh(float x) { return 1.f - 2.f / (__expf(2.f * x) + 1.f); }

// ---------------- init: zero states, hmax=-FLT_MAX, last[b] ----------------
// ws layout (floats): h0[2][H][B] | c0[H][B] | h1[2][H][B] | c1[H][B] | hmax[H][B] | last[B](int)
__global__ void k_init(float* __restrict__ ws, const int* __restrict__ X,
                       int* __restrict__ last) {
    int i = blockIdx.x * 256 + threadIdx.x;
    if (i < 6 * HB)       ws[i] = 0.f;
    else if (i < 7 * HB)  ws[i] = -FLT_MAX;
    if (i < B) {
        int l = -1;
        const int* xr = X + i * T;
        for (int t = 0; t < T; ++t)
            if (xr[t] != V) l = t;
        last[i] = l;
    }
}

// ---------------- pipelined GEMM core ----------------
// acc[jj][g]; weight rows r = jj*4+g -> row (g*H + j0+jj). Weight pointers carry an
// opaque runtime-zero so they live in VGPRs -> global_load_dwordx4 (all lanes same
// address -> single-line broadcast, deep VMEM miss queue).
// EMB=false: A is [K][B] pre-offset to lane's b.  EMB=true: A is lane's contiguous row.

__device__ __forceinline__ void fma_buf(float (&acc)[2][4], const float4 (&w)[8],
                                        const float (&a)[4]) {
#pragma unroll
    for (int r = 0; r < 8; ++r) {
        float4 wv = w[r];
        float ac = acc[r >> 2][r & 3];
        ac = fmaf(a[0], wv.x, ac);
        ac = fmaf(a[1], wv.y, ac);
        ac = fmaf(a[2], wv.z, ac);
        ac = fmaf(a[3], wv.w, ac);
        acc[r >> 2][r & 3] = ac;
    }
}

template <bool EMB>
__device__ __forceinline__ void load_a(float (&a)[4], const float* __restrict__ A, int q) {
    if (EMB) {
        float4 v = ((const float4*)A)[q];
        a[0] = v.x; a[1] = v.y; a[2] = v.z; a[3] = v.w;
    } else {
        const float* p = A + (size_t)q * 4 * B;
        a[0] = p[0 * B]; a[1] = p[1 * B]; a[2] = p[2 * B]; a[3] = p[3 * B];
    }
}

template <bool EMB>
__device__ __forceinline__ void gemm_pipe(float (&acc)[2][4], const float* __restrict__ A,
                                          const float4* const (&wr)[8], const int K4) {
    float4 w0[8], w1[8];
    float  a0[4], a1[4];
#pragma unroll
    for (int r = 0; r < 8; ++r) w0[r] = wr[r][0];
    load_a<EMB>(a0, A, 0);
#pragma unroll
    for (int r = 0; r < 8; ++r) w1[r] = wr[r][1];
    load_a<EMB>(a1, A, 1);

    for (int q = 0; q < K4; q += 2) {
        fma_buf(acc, w0, a0);
        if (q + 2 < K4) {
#pragma unroll
            for (int r = 0; r < 8; ++r) w0[r] = wr[r][q + 2];
            load_a<EMB>(a0, A, q + 2);
        }
        if (q + 1 < K4) {
            fma_buf(acc, w1, a1);
            if (q + 3 < K4) {
#pragma unroll
                for (int r = 0; r < 8; ++r) w1[r] = wr[r][q + 3];
                load_a<EMB>(a1, A, q + 3);
            }
        }
    }
}

__device__ __forceinline__ void epilogue(float (&acc)[2][4], const float* __restrict__ bias,
                                         int j0, float* __restrict__ c,
                                         float* __restrict__ hn, int b,
                                         float* __restrict__ hmax,
                                         const int* __restrict__ last, int tt) {
#pragma unroll
    for (int jj = 0; jj < 2; ++jj) {
        int j = j0 + jj;
        float gi = fsig (acc[jj][0] + bias[0 * H + j]);
        float gf = fsig (acc[jj][1] + bias[1 * H + j]);
        float gg = ftanh(acc[jj][2] + bias[2 * H + j]);
        float go = fsig (acc[jj][3] + bias[3 * H + j]);
        float cp = c[j * B + b];
        float cn = gf * cp + gi * gg;
        float hv = go * ftanh(cn);
        c[j * B + b]  = cn;
        hn[j * B + b] = hv;
        if (hmax != nullptr) {
            if (tt <= last[b]) {
                float m = hmax[j * B + b];
                hmax[j * B + b] = fmaxf(m, hv);
            }
        }
    }
}

// ---------------- combined step kernel ----------------
// blockIdx encoding (XCD-affinity): bid = slot*8 + xcd, xcd = jt&7.
//   slot = layer*32 + (jt>>3)*4 + bt
// so each XCD owns j-tiles {jt : jt&7 == xcd} for BOTH layers (~1.7 MB weights),
// and all 4 b-tiles of a j-tile hit the same XCD's L2 every step.
__global__ __launch_bounds__(256, 2) void k_step(
    int t,
    const int* __restrict__ X, const float* __restrict__ emb,
    const float* __restrict__ Wih0, const float* __restrict__ Whh0,
    const float* __restrict__ b0,
    const float* __restrict__ Wih1, const float* __restrict__ Whh1,
    const float* __restrict__ b1,
    float* __restrict__ ws)
{
    const int lane = threadIdx.x & 63;
    const int w    = __builtin_amdgcn_readfirstlane((int)(threadIdx.x >> 6)); // 0..3
    const int zr   = __shfl((int)(threadIdx.x & 63), 0) * 0 +
                     (__shfl((int)lane, 0));  // runtime 0, opaque to uniformity analysis

    const int bid  = blockIdx.x;
    const int xcd  = bid & 7;
    const int slot = bid >> 3;
    const bool isL1 = slot >= 32;
    const int  s2   = slot & 31;
    const int  bt   = s2 & 3;
    const int  jt   = ((s2 >> 2) << 3) | xcd;   // 0..63

    float* h0   = ws;                 // 2 slots
    float* c0   = ws + 2 * HB;
    float* h1   = ws + 3 * HB;        // 2 slots
    float* c1   = ws + 5 * HB;
    float* hmax = ws + 6 * HB;
    const int* last = (const int*)(ws + 7 * HB);

    const int j0 = jt * 8 + 2 * w;    // wave's first j
    const int b  = bt * 64 + lane;    // lane's batch row

    float acc[2][4] = {{0.f, 0.f, 0.f, 0.f}, {0.f, 0.f, 0.f, 0.f}};

    if (!isL1) {
        if (t >= T) return;
        const float* A_h = h0 + ((t + 1) & 1) * HB + b;   // h0[t-1]
        float*       hn  = h0 + (t & 1) * HB;             // h0[t]

        const float4* wx[8];
        const float4* wh[8];
#pragma unroll
        for (int r = 0; r < 8; ++r) {
            int row = (r & 3) * H + j0 + (r >> 2);
            wx[r] = (const float4*)(Wih0 + (size_t)row * E) + zr;
            wh[r] = (const float4*)(Whh0 + (size_t)row * H) + zr;
        }
        const float* er = emb + (size_t)X[b * T + t] * E;
        gemm_pipe<true >(acc, er,  wx, E / 4);   // 25 (odd: tail handled)
        gemm_pipe<false>(acc, A_h, wh, H / 4);   // 128
        epilogue(acc, b0, j0, c0, hn, b, nullptr, nullptr, 0);
    } else {
        if (t < 1) return;
        const int tt = t - 1;
        const float* A_x = h0 + (tt & 1) * HB + b;        // x = h0[tt]
        const float* A_h = h1 + ((tt + 1) & 1) * HB + b;  // h1[tt-1]
        float*       hn  = h1 + (tt & 1) * HB;            // h1[tt]

        const float4* wx[8];
        const float4* wh[8];
#pragma unroll
        for (int r = 0; r < 8; ++r) {
            int row = (r & 3) * H + j0 + (r >> 2);
            wx[r] = (const float4*)(Wih1 + (size_t)row * H) + zr;
            wh[r] = (const float4*)(Whh1 + (size_t)row * H) + zr;
        }
        gemm_pipe<false>(acc, A_x, wx, H / 4);
        gemm_pipe<false>(acc, A_h, wh, H / 4);
        epilogue(acc, b1, j0, c1, hn, b, hmax, last, tt);
    }
}

// ---------------- final: logits[b][cls] = sum_j hmax[j][b] * Wout[cls][j] + bout ----
__global__ __launch_bounds__(64) void k_out(const float* __restrict__ hmax,
                                            const float* __restrict__ Wout,
                                            const float* __restrict__ bout,
                                            float* __restrict__ out) {
    const int b = blockIdx.x * 64 + threadIdx.x;
    float a[NC] = {0.f, 0.f, 0.f, 0.f, 0.f};
    const float* hm = hmax + b;
    for (int j = 0; j < H; ++j) {
        float hv = hm[j * B];
#pragma unroll
        for (int cls = 0; cls < NC; ++cls)
            a[cls] = fmaf(hv, Wout[cls * H + j], a[cls]);
    }
#pragma unroll
    for (int cls = 0; cls < NC; ++cls)
        out[b * NC + cls] = a[cls] + bout[cls];
}

// ---------------- launch ----------------
extern "C" void kernel_launch(void* const* d_in, const int* in_sizes, int n_in,
                              void* d_out, int out_size, void* d_ws, size_t ws_size,
                              hipStream_t stream) {
    const int*   X    = (const int*)  d_in[0];
    const float* emb  = (const float*)d_in[1];
    const float* Wih0 = (const float*)d_in[2];
    const float* Whh0 = (const float*)d_in[3];
    const float* b0   = (const float*)d_in[4];
    const float* Wih1 = (const float*)d_in[5];
    const float* Whh1 = (const float*)d_in[6];
    const float* b1   = (const float*)d_in[7];
    const float* Wout = (const float*)d_in[8];
    const float* bout = (const float*)d_in[9];
    float* out = (float*)d_out;
    float* ws  = (float*)d_ws;

    float* hmax = ws + 6 * HB;
    int*   last = (int*)(ws + 7 * HB);

    k_init<<<(7 * HB + 255) / 256, 256, 0, stream>>>(ws, X, last);

    // Launch L_t computes layer0(t) and layer1(t-1); t = 0..T inclusive.
    for (int t = 0; t <= T; ++t) {
        k_step<<<512, 256, 0, stream>>>(t, X, emb, Wih0, Whh0, b0,
                                        Wih1, Whh1, b1, ws);
    }

    k_out<<<4, 64, 0, stream>>>(hmax, Wout, bout, out);
}

// Round 4
// 7405.639 us; speedup vs baseline: 3.5840x; 3.5840x over previous
//
#include <hip/hip_runtime.h>
#include <float.h>

#define V 50000
#define E 100
#define H 512
#define T 200
#define B 256
#define NC 5
#define HB (H * B)

// ---------------- activations (fast, ~2e-7 abs err) ----------------
__device__ __forceinline__ float fsig(float x)  { return 1.f / (1.f + __expf(-x)); }
__device__ __forceinline__ float ftanh(float x) { return 1.f - 2.f / (__expf(2.f * x) + 1.f); }

// ---------------- init: zero states, hmax=-FLT_MAX, last[b] ----------------
// ws layout (floats): h0[2][H][B] | c0[H][B] | h1[2][H][B] | c1[H][B] | hmax[H][B] | last[B](int)
__global__ void k_init(float* __restrict__ ws, const int* __restrict__ X,
                       int* __restrict__ last) {
    int i = blockIdx.x * 256 + threadIdx.x;
    if (i < 6 * HB)       ws[i] = 0.f;
    else if (i < 7 * HB)  ws[i] = -FLT_MAX;
    if (i < B) {
        int l = -1;
        const int* xr = X + i * T;
        for (int t = 0; t < T; ++t)
            if (xr[t] != V) l = t;
        last[i] = l;
    }
}

// ---------------- staging helpers (per half-block: 128 threads) ----------------
// xS: [64][32]  (k-major, b minor)    wS: [64][64]  (k-major, c = jl*4+g minor)

__device__ __forceinline__ void stage_x_rec(float* __restrict__ xS,
                                            const float* __restrict__ A,
                                            int kbase, int b0g, int tid2) {
    const int kl0 = tid2 >> 3;            // 0..15
    const int b4  = (tid2 & 7) * 4;       // 0..28
#pragma unroll
    for (int q = 0; q < 4; ++q) {
        int kl = kl0 + q * 16;
        float4 v = *(const float4*)(A + (size_t)(kbase + kl) * B + b0g + b4);
        *(float4*)(xS + kl * 32 + b4) = v;
    }
}

__device__ __forceinline__ void stage_x_emb(float* __restrict__ xS,
                                            const float* __restrict__ emb,
                                            const int* __restrict__ X, int t,
                                            int b0g, int kbase, int tid2) {
    const int b_l = tid2 & 31;
    const int kg  = tid2 >> 5;            // 0..3
    const int row = X[(b0g + b_l) * T + t];
    const float* er = emb + (size_t)row * E;
#pragma unroll
    for (int q = 0; q < 4; ++q) {
        int k = kbase + kg * 4 + q * 16;  // multiple of 4
        float4 v = make_float4(0.f, 0.f, 0.f, 0.f);
        if (k < E) v = *(const float4*)(er + k);   // k=96 reads 96..99, in-row
        int kl = k - kbase;
        xS[(kl + 0) * 32 + b_l] = v.x;
        xS[(kl + 1) * 32 + b_l] = v.y;
        xS[(kl + 2) * 32 + b_l] = v.z;
        xS[(kl + 3) * 32 + b_l] = v.w;
    }
}

__device__ __forceinline__ void stage_w(float* __restrict__ wS,
                                        const float* __restrict__ Wm, int ld, int Klim,
                                        int jt, int kbase, int tid2) {
    const int c_l = tid2 & 63;            // c = jl*4 + g
    const int kh  = tid2 >> 6;            // 0/1
    const int jl  = c_l >> 2;
    const int g   = c_l & 3;
    const int row = g * H + jt * 16 + jl;
    const float* wr = Wm + (size_t)row * ld;
#pragma unroll
    for (int q = 0; q < 8; ++q) {
        int k  = kbase + kh * 32 + q * 4;
        int kl = kh * 32 + q * 4;
        float4 v = make_float4(0.f, 0.f, 0.f, 0.f);
        if (k < Klim) v = *(const float4*)(wr + k);
        wS[(kl + 0) * 64 + c_l] = v.x;    // 2-way bank alias: free
        wS[(kl + 1) * 64 + c_l] = v.y;
        wS[(kl + 2) * 64 + c_l] = v.z;
        wS[(kl + 3) * 64 + c_l] = v.w;
    }
}

// ---------------- fused step kernel ----------------
// 512 blocks: gid = layer*32 + jt (j-tile of 16), bt = b-tile of 32 (8 tiles).
// bid = (((gid>>3)*8) + bt)*8 + (gid&7)  -> XCD-affinity: all 8 b-tiles of a
// j-tile (and its weights, ~1.6 MB/XCD) pin to one XCD's L2.
// Within a block: half 0 (tid<128) and half 1 (tid>=128) each compute the full
// 32b x 16j x 4gate tile over half of K; LDS reduction at the end.
__global__ __launch_bounds__(256, 2) void k_step(
    int t,
    const int* __restrict__ X, const float* __restrict__ emb,
    const float* __restrict__ Wih0, const float* __restrict__ Whh0,
    const float* __restrict__ b0,
    const float* __restrict__ Wih1, const float* __restrict__ Whh1,
    const float* __restrict__ b1,
    float* __restrict__ ws)
{
    __shared__ float smem[12288];   // 48 KB

    const int tid  = threadIdx.x;
    const int half = tid >> 7;
    const int tid2 = tid & 127;

    const int xcd = blockIdx.x & 7;
    const int r   = blockIdx.x >> 3;
    const int bt  = r & 7;
    const int gid = ((r >> 3) << 3) | xcd;
    const int layer = gid >> 5;
    const int jt    = gid & 31;

    if (layer == 0 && t >= T) return;
    if (layer == 1 && t == 0) return;
    const int tt = t - 1;   // layer1 time index

    float* h0   = ws;
    float* c0   = ws + 2 * HB;
    float* h1   = ws + 3 * HB;
    float* c1   = ws + 5 * HB;
    float* hmax = ws + 6 * HB;
    const int* last = (const int*)(ws + 7 * HB);

    float* xSh = smem + (half ? 6144 : 0);
    float* wSh = smem + (half ? 8192 : 2048);

    const int b0g  = bt * 32;
    const int bthr = tid2 >> 4;     // 0..7
    const int jthr = tid2 & 15;

    float acc[4][4] = {{0,0,0,0},{0,0,0,0},{0,0,0,0},{0,0,0,0}};

    const float* h0prev = h0 + ((t + 1) & 1) * HB;   // h0[t-1]
    const int NCH = layer ? 8 : 5;

    for (int ch = 0; ch < NCH; ++ch) {
        if (layer == 1) {
            const float* A = half ? (h1 + ((tt + 1) & 1) * HB)   // h1[tt-1]
                                  : (h0 + (tt & 1) * HB);        // x = h0[tt]
            const float* W = half ? Whh1 : Wih1;
            stage_x_rec(xSh, A, ch * 64, b0g, tid2);
            stage_w(wSh, W, H, 1 << 20, jt, ch * 64, tid2);
        } else {
            if (half == 0) {
                if (ch < 2) {   // embedding part, K=100 padded to 128
                    stage_x_emb(xSh, emb, X, t, b0g, ch * 64, tid2);
                    stage_w(wSh, Wih0, E, E, jt, ch * 64, tid2);
                } else {        // recurrent k 0..191
                    stage_x_rec(xSh, h0prev, (ch - 2) * 64, b0g, tid2);
                    stage_w(wSh, Whh0, H, 1 << 20, jt, (ch - 2) * 64, tid2);
                }
            } else {            // recurrent k 192..511
                stage_x_rec(xSh, h0prev, 192 + ch * 64, b0g, tid2);
                stage_w(wSh, Whh0, H, 1 << 20, jt, 192 + ch * 64, tid2);
            }
        }
        __syncthreads();

        const float* xp = xSh + bthr * 4;
        const float* wp = wSh + jthr * 4;
#pragma unroll 8
        for (int k = 0; k < 64; ++k) {
            float4 xv = *(const float4*)(xp + k * 32);   // 16-lane broadcast
            float4 wv = *(const float4*)(wp + k * 64);   // conflict-free
            acc[0][0] = fmaf(xv.x, wv.x, acc[0][0]);
            acc[0][1] = fmaf(xv.x, wv.y, acc[0][1]);
            acc[0][2] = fmaf(xv.x, wv.z, acc[0][2]);
            acc[0][3] = fmaf(xv.x, wv.w, acc[0][3]);
            acc[1][0] = fmaf(xv.y, wv.x, acc[1][0]);
            acc[1][1] = fmaf(xv.y, wv.y, acc[1][1]);
            acc[1][2] = fmaf(xv.y, wv.z, acc[1][2]);
            acc[1][3] = fmaf(xv.y, wv.w, acc[1][3]);
            acc[2][0] = fmaf(xv.z, wv.x, acc[2][0]);
            acc[2][1] = fmaf(xv.z, wv.y, acc[2][1]);
            acc[2][2] = fmaf(xv.z, wv.z, acc[2][2]);
            acc[2][3] = fmaf(xv.z, wv.w, acc[2][3]);
            acc[3][0] = fmaf(xv.w, wv.x, acc[3][0]);
            acc[3][1] = fmaf(xv.w, wv.y, acc[3][1]);
            acc[3][2] = fmaf(xv.w, wv.z, acc[3][2]);
            acc[3][3] = fmaf(xv.w, wv.w, acc[3][3]);
        }
        __syncthreads();
    }

    // ---- reduce the two K-halves (redS overlays half-0's dead xS) ----
    float* redS = smem;
    if (half == 1) {
#pragma unroll
        for (int bb = 0; bb < 4; ++bb)
            *(float4*)(redS + tid2 * 16 + bb * 4) =
                make_float4(acc[bb][0], acc[bb][1], acc[bb][2], acc[bb][3]);
    }
    __syncthreads();

    if (half == 0) {
        const int j   = jt * 16 + jthr;
        const int bb0 = b0g + bthr * 4;
        float* cst        = layer ? c1 : c0;
        float* hout       = layer ? (h1 + (tt & 1) * HB) : (h0 + (t & 1) * HB);
        const float* bias = layer ? b1 : b0;

        const float bi = bias[0 * H + j];
        const float bf = bias[1 * H + j];
        const float bg = bias[2 * H + j];
        const float bo = bias[3 * H + j];

        float4 cp = *(const float4*)(cst + (size_t)j * B + bb0);
        float cpa[4] = {cp.x, cp.y, cp.z, cp.w};
        float cn[4], hn[4];
#pragma unroll
        for (int bb = 0; bb < 4; ++bb) {
            float4 o = *(const float4*)(redS + tid2 * 16 + bb * 4);
            float gi = fsig (acc[bb][0] + o.x + bi);
            float gf = fsig (acc[bb][1] + o.y + bf);
            float gg = ftanh(acc[bb][2] + o.z + bg);
            float go = fsig (acc[bb][3] + o.w + bo);
            cn[bb] = gf * cpa[bb] + gi * gg;
            hn[bb] = go * ftanh(cn[bb]);
        }
        *(float4*)(cst  + (size_t)j * B + bb0) = make_float4(cn[0], cn[1], cn[2], cn[3]);
        *(float4*)(hout + (size_t)j * B + bb0) = make_float4(hn[0], hn[1], hn[2], hn[3]);
        if (layer == 1) {
#pragma unroll
            for (int bb = 0; bb < 4; ++bb) {
                int b = bb0 + bb;
                if (tt <= last[b]) {
                    float m = hmax[(size_t)j * B + b];
                    hmax[(size_t)j * B + b] = fmaxf(m, hn[bb]);
                }
            }
        }
    }
}

// ---------------- final: logits[b][cls] = sum_j hmax[j][b] * Wout[cls][j] + bout ----
__global__ __launch_bounds__(64) void k_out(const float* __restrict__ hmax,
                                            const float* __restrict__ Wout,
                                            const float* __restrict__ bout,
                                            float* __restrict__ out) {
    const int b = blockIdx.x * 64 + threadIdx.x;
    float a[NC] = {0.f, 0.f, 0.f, 0.f, 0.f};
    const float* hm = hmax + b;
    for (int j = 0; j < H; ++j) {
        float hv = hm[j * B];
#pragma unroll
        for (int cls = 0; cls < NC; ++cls)
            a[cls] = fmaf(hv, Wout[cls * H + j], a[cls]);
    }
#pragma unroll
    for (int cls = 0; cls < NC; ++cls)
        out[b * NC + cls] = a[cls] + bout[cls];
}

// ---------------- launch ----------------
extern "C" void kernel_launch(void* const* d_in, const int* in_sizes, int n_in,
                              void* d_out, int out_size, void* d_ws, size_t ws_size,
                              hipStream_t stream) {
    const int*   X    = (const int*)  d_in[0];
    const float* emb  = (const float*)d_in[1];
    const float* Wih0 = (const float*)d_in[2];
    const float* Whh0 = (const float*)d_in[3];
    const float* b0   = (const float*)d_in[4];
    const float* Wih1 = (const float*)d_in[5];
    const float* Whh1 = (const float*)d_in[6];
    const float* b1   = (const float*)d_in[7];
    const float* Wout = (const float*)d_in[8];
    const float* bout = (const float*)d_in[9];
    float* out = (float*)d_out;
    float* ws  = (float*)d_ws;

    float* hmax = ws + 6 * HB;
    int*   last = (int*)(ws + 7 * HB);

    k_init<<<(7 * HB + 255) / 256, 256, 0, stream>>>(ws, X, last);

    // Dispatch t computes layer0(t) and layer1(t-1); t = 0..T inclusive.
    for (int t = 0; t <= T; ++t) {
        k_step<<<512, 256, 0, stream>>>(t, X, emb, Wih0, Whh0, b0,
                                        Wih1, Whh1, b1, ws);
    }

    k_out<<<4, 64, 0, stream>>>(hmax, Wout, bout, out);
}